// Round 3
// baseline (82.616 us; speedup 1.0000x reference)
//
#include <hip/hip_runtime.h>

// Causal linear attention (ELU+1), chunked bf16-MFMA, 3 plain launches.
// R11 = R10 with parallelism/vectorization fixes (R10 post-mortem: k_out
// staging diet was neutral -> bottleneck is latency/occupancy elsewhere):
//  k1    (NC,B,4): now 256 blocks (v-half x i-half) -- R10's 128 blocks left
//         half the CUs idle in the longest kernel. Each block: half-V+half-K,
//         swizzled LDS transpose -> S_c^T quadrant + ksum; dumps phiK bf16
//         (KB, vs==0) and swizzled V^T bf16 (VT, is==0).
//  k_scan: vectorized uint4 (8 elems/thread, 32 independent loads, 1 wait);
//         was 2B/lane scalar loads (8x under-vectorized).
//  k_out (NC,B,4): R10 structure + T14 split of SB restage (issue global
//         loads before GEMM2, ds_write after S1 -> L2 latency hidden).
// Swizzle: elem (l, row) stored at col ((l>>3 + row>>2)&15)*8 + (l&7);
// read frag (row, kq) at ((kq + row>>2)&15)*8  (verified in R7's k_fused).
// Harness floor ~46us (256MB ws poison fill + input restore); cooperative
// launch adds ~30us replay overhead (R7) -- avoided.

#define EPS 1e-6f

constexpr int Bc = 2;
constexpr int L  = 4096;
constexpr int D  = 128;
constexpr int C  = 128;
constexpr int NC = L / C;   // 32
constexpr int P  = 136;     // LDS row pitch (bf16), rows 16B-aligned

typedef short sh8 __attribute__((ext_vector_type(8)));
typedef float f4  __attribute__((ext_vector_type(4)));

__device__ __forceinline__ float phi(float x) {
    return x > 0.0f ? x + 1.0f : __expf(x);
}
__device__ __forceinline__ unsigned short f2bf(float f) {
    unsigned u = __float_as_uint(f);
    return (unsigned short)((u + 0x7FFFu + ((u >> 16) & 1u)) >> 16);  // RNE
}
__device__ __forceinline__ float bf2f(unsigned short h) {
    return __uint_as_float(((unsigned)h) << 16);
}
__device__ __forceinline__ unsigned packbf(float a, float b) {
    return (unsigned)f2bf(a) | ((unsigned)f2bf(b) << 16);
}
__device__ __forceinline__ sh8 splat1() {
    sh8 s;
#pragma unroll
    for (int j = 0; j < 8; ++j) s[j] = (short)0x3F80;
    return s;
}

// ---------------------------------------------------------------------------
// k1 (NC,B,4), 512 thr: z = (is<<1)|vs.  Block computes S_c^T quadrant
// [vs half of v][is half of i] = sum_l V[l][v] phiK[l][i]; plus ksum (vs==0),
// KB dump (vs==0), VT dump (is==0).  All global reads coalesced; transposes
// in LDS via swizzle.  LDS 34.8KB.
// ---------------------------------------------------------------------------
__global__ __launch_bounds__(512) void k1(
    const float* __restrict__ K, const float* __restrict__ V,
    unsigned short* __restrict__ SB, float* __restrict__ Ksum,
    unsigned short* __restrict__ KB, unsigned short* __restrict__ VT) {
    const int c = blockIdx.x, b = blockIdx.y;
    const int vs = blockIdx.z & 1, is = blockIdx.z >> 1;
    const int tid = threadIdx.x;
    __shared__ __align__(16) unsigned short sVT[64 * P];   // V^T slice [vr][l]
    __shared__ __align__(16) unsigned short sKT[64 * P];   // phiK^T slice [ir][l]
    const size_t base = ((size_t)b * L + (size_t)c * C) * D;

    // V slice: 128 rows x 64 cols (at vs*64) f32 = 2048 float4, coalesced
    for (int k = 0; k < 4; ++k) {
        int fi = tid + 512 * k;
        int l = fi >> 4, c4 = fi & 15;      // c4: 16 float4 per row-slice
        float4 vd = *(const float4*)(V + base + (size_t)l * D + vs * 64 + c4 * 4);
        int blk = (((l >> 3) + c4) & 15) * 8 + (l & 7);   // (c4*4+s)>>2 == c4
        sVT[(c4 * 4 + 0) * P + blk] = f2bf(vd.x);
        sVT[(c4 * 4 + 1) * P + blk] = f2bf(vd.y);
        sVT[(c4 * 4 + 2) * P + blk] = f2bf(vd.z);
        sVT[(c4 * 4 + 3) * P + blk] = f2bf(vd.w);
    }
    // K slice: 128 rows x 64 cols (at is*64) f32 = 2048 float4, coalesced,
    // phi applied.  vs==0 also streams packed bf16 out to KB (uint2).
    for (int k = 0; k < 4; ++k) {
        int fi = tid + 512 * k;
        int l = fi >> 4, i4 = fi & 15;
        float4 kd = *(const float4*)(K + base + (size_t)l * D + is * 64 + i4 * 4);
        int blk = (((l >> 3) + i4) & 15) * 8 + (l & 7);
        unsigned short h0 = f2bf(phi(kd.x)), h1 = f2bf(phi(kd.y));
        unsigned short h2 = f2bf(phi(kd.z)), h3 = f2bf(phi(kd.w));
        sKT[(i4 * 4 + 0) * P + blk] = h0;
        sKT[(i4 * 4 + 1) * P + blk] = h1;
        sKT[(i4 * 4 + 2) * P + blk] = h2;
        sKT[(i4 * 4 + 3) * P + blk] = h3;
        if (vs == 0) {
            uint2 pk;
            pk.x = (unsigned)h0 | ((unsigned)h1 << 16);
            pk.y = (unsigned)h2 | ((unsigned)h3 << 16);
            *(uint2*)(KB + base + (size_t)l * D + is * 64 + i4 * 4) = pk;
        }
    }
    __syncthreads();

    // dump swizzled V^T image (64 rows, compact pitch 128); is==0 blocks only.
    if (is == 0) {
        const size_t vtb = (size_t)(b * NC + c) * D * 128 + (size_t)vs * 64 * 128;
        for (int k = 0; k < 2; ++k) {
            int idx = tid + 512 * k;
            int vr = idx >> 4, c8 = idx & 15;
            *(uint4*)(VT + vtb + vr * 128 + c8 * 8) =
                *(const uint4*)(sVT + vr * P + c8 * 8);
        }
    }

    const int w = tid >> 6, lane = tid & 63;
    const int r = lane & 15, q = lane >> 4;
    const int rbase = (w & 3) * 16;        // v rows within 64
    const int cbase = (w >> 2) * 32;       // i cols within 64
    const bool doK = ((w & 3) == 0) && (vs == 0);  // waves 0 (i 0..31), 4 (32..63)
    const sh8 ones = splat1();

    f4 acc[2], kz[2];
#pragma unroll
    for (int f = 0; f < 2; ++f) { acc[f] = {0.f,0.f,0.f,0.f}; kz[f] = {0.f,0.f,0.f,0.f}; }
#pragma unroll
    for (int ks = 0; ks < 4; ++ks) {
        int kq = ks * 4 + q;
        int vr = rbase + r;
        sh8 a = *(const sh8*)(sVT + vr * P + ((kq + (vr >> 2)) & 15) * 8);
#pragma unroll
        for (int f = 0; f < 2; ++f) {
            int ir = cbase + f * 16 + r;
            sh8 bk = *(const sh8*)(sKT + ir * P + ((kq + (ir >> 2)) & 15) * 8);
            acc[f] = __builtin_amdgcn_mfma_f32_16x16x32_bf16(a, bk, acc[f], 0, 0, 0);
            if (doK) kz[f] = __builtin_amdgcn_mfma_f32_16x16x32_bf16(ones, bk, kz[f], 0, 0, 0);
        }
    }
    unsigned short* out = SB + ((size_t)(b * NC + c)) * D * D;
#pragma unroll
    for (int f = 0; f < 2; ++f) {
        int i = is * 64 + cbase + f * 16 + r;
#pragma unroll
        for (int e = 0; e < 4; ++e) {
            int v = vs * 64 + rbase + q * 4 + e;
            out[(size_t)v * D + i] = f2bf(acc[f][e]);
        }
    }
    if (doK && q == 0) {                   // colsum rows identical; row 0
#pragma unroll
        for (int f = 0; f < 2; ++f)
            Ksum[((size_t)(b * NC + c)) * D + is * 64 + cbase + f * 16 + r] = kz[f][0];
    }
}

// ---------------------------------------------------------------------------
// k_scan: exclusive prefix over chunks, vectorized: uint4 (8 bf16) per
// thread for SB, float4 per thread for Ksum.  32 independent loads in
// flight per thread, one latency wait, then prefix+store.
// ---------------------------------------------------------------------------
__global__ __launch_bounds__(256) void k_scan(unsigned short* __restrict__ SB,
                                              float* __restrict__ Ksum) {
    const int SD = D * D;                  // 16384
    const int nSB = Bc * SD / 8;           // 4096 threads
    int idx = blockIdx.x * 256 + threadIdx.x;
    if (idx < nSB) {
        int b = idx / (SD / 8), e8 = idx % (SD / 8);
        size_t off0 = (size_t)b * NC * SD + (size_t)e8 * 8;  // ushort index
        uint4 vals[NC];
#pragma unroll
        for (int c = 0; c < NC; ++c)
            vals[c] = *(const uint4*)(SB + off0 + (size_t)c * SD);
        float run[8];
#pragma unroll
        for (int j = 0; j < 8; ++j) run[j] = 0.0f;
#pragma unroll
        for (int c = 0; c < NC; ++c) {
            uint4 w;
            w.x = packbf(run[0], run[1]);
            w.y = packbf(run[2], run[3]);
            w.z = packbf(run[4], run[5]);
            w.w = packbf(run[6], run[7]);
            *(uint4*)(SB + off0 + (size_t)c * SD) = w;
            run[0] += bf2f((unsigned short)(vals[c].x & 0xFFFF));
            run[1] += bf2f((unsigned short)(vals[c].x >> 16));
            run[2] += bf2f((unsigned short)(vals[c].y & 0xFFFF));
            run[3] += bf2f((unsigned short)(vals[c].y >> 16));
            run[4] += bf2f((unsigned short)(vals[c].z & 0xFFFF));
            run[5] += bf2f((unsigned short)(vals[c].z >> 16));
            run[6] += bf2f((unsigned short)(vals[c].w & 0xFFFF));
            run[7] += bf2f((unsigned short)(vals[c].w >> 16));
        }
    } else if (idx < nSB + Bc * D / 4) {   // 64 threads
        int rr = idx - nSB;
        int b = rr >> 5, i4 = rr & 31;
        size_t off0 = (size_t)b * NC * D + (size_t)i4 * 4;
        float4 vals[NC];
#pragma unroll
        for (int c = 0; c < NC; ++c)
            vals[c] = *(const float4*)(Ksum + off0 + (size_t)c * D);
        float4 run = {0.f, 0.f, 0.f, 0.f};
#pragma unroll
        for (int c = 0; c < NC; ++c) {
            *(float4*)(Ksum + off0 + (size_t)c * D) = run;
            run.x += vals[c].x; run.y += vals[c].y;
            run.z += vals[c].z; run.w += vals[c].w;
        }
    }
}

// ---------------------------------------------------------------------------
// k_out (NC,B,4), rows split 4x32, 512 thr (8 waves: rbase=(w&1)*16,
// col quarter cq=w>>1).  Staging is straight bf16 uint4 copies (KB/VT);
// phiQ in register frags (reused by GEMM2+GEMM4); MFMA B-frags from LDS
// (ds_read_b128, conflict-free).  SB restage T14-split: loads issued before
// GEMM2, ds_writes after S1 (L2 latency hidden under GEMM2).
// LDS = sK + sVT + sAm + sZ = 78.5KB.  z fully in MFMA.
// ---------------------------------------------------------------------------
__global__ __launch_bounds__(512) void k_out(
    const float* __restrict__ Q, const unsigned short* __restrict__ KB,
    const unsigned short* __restrict__ VT, const unsigned short* __restrict__ SB,
    const float* __restrict__ Ksum, float* __restrict__ Out) {
    const int c = blockIdx.x, b = blockIdx.y, rs = blockIdx.z;
    const int tid = threadIdx.x;
    __shared__ __align__(16) unsigned short sK[128 * P];   // phiK rows -> S^T
    __shared__ __align__(16) unsigned short sVT[128 * P];  // V^T swizzled
    __shared__ __align__(16) unsigned short sAm[32 * P];   // masked A
    __shared__ float sZ[32];
    const size_t obase = ((size_t)b * L + (size_t)c * C) * D;  // f32 Q / Out, KB elems
    const size_t tbase = (size_t)(b * NC + c) * (size_t)D * D; // SB chunk
    const size_t vtb   = (size_t)(b * NC + c) * (size_t)D * 128;
    const size_t kb    = (size_t)(b * NC + c) * D;             // Ksum

    // stage sK <- phiK bf16 rows (2048 uint4, coalesced)
    for (int k = 0; k < 4; ++k) {
        int fi = tid + 512 * k;
        int row = fi >> 4, c8 = fi & 15;
        *(uint4*)(sK + row * P + c8 * 8) =
            *(const uint4*)(KB + obase + (size_t)row * D + c8 * 8);
    }
    // stage sVT <- swizzled V^T image (2048 uint4, coalesced)
    for (int k = 0; k < 4; ++k) {
        int fi = tid + 512 * k;
        int vr = fi >> 4, c8 = fi & 15;
        *(uint4*)(sVT + vr * P + c8 * 8) =
            *(const uint4*)(VT + vtb + (size_t)vr * 128 + c8 * 8);
    }

    // T14 split: issue SB restage loads NOW, ds_write after S1.
    uint4 sbv[4];
    {
        const uint4* sg = (const uint4*)(SB + tbase);
#pragma unroll
        for (int k = 0; k < 4; ++k) sbv[k] = sg[tid + 512 * k];
    }

    const int w = tid >> 6, lane = tid & 63;
    const int r = lane & 15, q = lane >> 4;
    const int rbase = (w & 1) * 16;
    const int cq = w >> 1, cbase = cq * 32;
    const bool doZ = (cq == 3);            // rows covered by w=6 (rbase 0), w=7 (16)

    // phiQ frags in registers (row = rs*32 + rbase + r, k = ks*32 + q*8 .. +7)
    sh8 qf[4];
    {
        const float* qrow = Q + obase + (size_t)(rs * 32 + rbase + r) * D;
#pragma unroll
        for (int ks = 0; ks < 4; ++ks) {
            float4 a0 = *(const float4*)(qrow + ks * 32 + q * 8);
            float4 a1 = *(const float4*)(qrow + ks * 32 + q * 8 + 4);
            sh8 t;
            t[0] = (short)f2bf(phi(a0.x)); t[1] = (short)f2bf(phi(a0.y));
            t[2] = (short)f2bf(phi(a0.z)); t[3] = (short)f2bf(phi(a0.w));
            t[4] = (short)f2bf(phi(a1.x)); t[5] = (short)f2bf(phi(a1.y));
            t[6] = (short)f2bf(phi(a1.z)); t[7] = (short)f2bf(phi(a1.w));
            qf[ks] = t;
        }
    }

    // kprev B-frags for GEMM4 z (r-invariant; L2-hot)
    sh8 bzk[4];
    if (doZ) {
#pragma unroll
        for (int ks = 0; ks < 4; ++ks) {
            float4 f0 = *(const float4*)(Ksum + kb + ks * 32 + q * 8);
            float4 f1 = *(const float4*)(Ksum + kb + ks * 32 + q * 8 + 4);
            sh8 t;
            t[0] = (short)f2bf(f0.x); t[1] = (short)f2bf(f0.y);
            t[2] = (short)f2bf(f0.z); t[3] = (short)f2bf(f0.w);
            t[4] = (short)f2bf(f1.x); t[5] = (short)f2bf(f1.y);
            t[6] = (short)f2bf(f1.z); t[7] = (short)f2bf(f1.w);
            bzk[ks] = t;
        }
    }
    __syncthreads();                       // S0: sK, sVT staged

    // ---- GEMM2: A = phiQ phiK^T (B-frags from sK rows) ----
    f4 a2[2];
#pragma unroll
    for (int f = 0; f < 2; ++f) a2[f] = {0.f,0.f,0.f,0.f};
#pragma unroll
    for (int ks = 0; ks < 4; ++ks) {
#pragma unroll
        for (int f = 0; f < 2; ++f) {
            sh8 bb = *(const sh8*)(sK + (cbase + f * 16 + r) * P + ks * 32 + q * 8);
            a2[f] = __builtin_amdgcn_mfma_f32_16x16x32_bf16(qf[ks], bb, a2[f], 0, 0, 0);
        }
    }
#pragma unroll
    for (int f = 0; f < 2; ++f) {          // causal mask -> sAm bf16
        int j = cbase + f * 16 + r;
#pragma unroll
        for (int e = 0; e < 4; ++e) {
            int lr = rbase + q * 4 + e;
            sAm[lr * P + j] = f2bf((j <= rs * 32 + lr) ? a2[f][e] : 0.f);
        }
    }
    __syncthreads();                       // S1: sAm ready, sK GEMM2 reads done

    // restage sK <- S_prev^T (ds_writes only; loads issued pre-GEMM2)
#pragma unroll
    for (int k = 0; k < 4; ++k) {
        int f2 = tid + 512 * k;
        *(uint4*)(sK + (f2 >> 4) * P + (f2 & 15) * 8) = sbv[k];
    }

    // ---- GEMM3: acc = Am @ V (+ rowsum z via ones-B) ----
    f4 acc[2], zacc = {0.f,0.f,0.f,0.f};
#pragma unroll
    for (int f = 0; f < 2; ++f) acc[f] = {0.f,0.f,0.f,0.f};
    const sh8 ones = splat1();
#pragma unroll
    for (int ks = 0; ks < 4; ++ks) {
        int kq = ks * 4 + q;
        sh8 a = *(const sh8*)(sAm + (rbase + r) * P + ks * 32 + q * 8);
#pragma unroll
        for (int f = 0; f < 2; ++f) {
            int vr = cbase + f * 16 + r;
            sh8 bv = *(const sh8*)(sVT + vr * P + ((kq + (vr >> 2)) & 15) * 8);
            acc[f] = __builtin_amdgcn_mfma_f32_16x16x32_bf16(a, bv, acc[f], 0, 0, 0);
        }
        if (doZ) zacc = __builtin_amdgcn_mfma_f32_16x16x32_bf16(a, ones, zacc, 0, 0, 0);
    }
    __syncthreads();                       // S2: sK = S^T ready

    // ---- GEMM4: acc += phiQ @ S_prev (+ kprev z) ----
#pragma unroll
    for (int ks = 0; ks < 4; ++ks) {
#pragma unroll
        for (int f = 0; f < 2; ++f) {
            sh8 bs = *(const sh8*)(sK + (cbase + f * 16 + r) * P + ks * 32 + q * 8);
            acc[f] = __builtin_amdgcn_mfma_f32_16x16x32_bf16(qf[ks], bs, acc[f], 0, 0, 0);
        }
        if (doZ) zacc = __builtin_amdgcn_mfma_f32_16x16x32_bf16(qf[ks], bzk[ks], zacc, 0, 0, 0);
    }
    if (doZ && r == 0) {
#pragma unroll
        for (int e = 0; e < 4; ++e) sZ[rbase + q * 4 + e] = zacc[e] + EPS;
    }
    __syncthreads();                       // S3: sZ ready

    // ---- normalize + store ----
#pragma unroll
    for (int f = 0; f < 2; ++f) {
        int v = cbase + f * 16 + r;
#pragma unroll
        for (int e = 0; e < 4; ++e) {
            int lr = rbase + q * 4 + e;
            Out[obase + (size_t)(rs * 32 + lr) * D + v] = acc[f][e] / sZ[lr];
        }
    }
}

extern "C" void kernel_launch(void* const* d_in, const int* in_sizes, int n_in,
                              void* d_out, int out_size, void* d_ws, size_t ws_size,
                              hipStream_t stream) {
    const float* Q = (const float*)d_in[0];
    const float* K = (const float*)d_in[1];
    const float* V = (const float*)d_in[2];
    float* Out = (float*)d_out;
    const size_t SB_BYTES = (size_t)Bc * NC * D * D * 2;   // 2 MB
    unsigned short* SBw = (unsigned short*)d_ws;                         // 2 MB
    unsigned short* KBw = (unsigned short*)((char*)d_ws + SB_BYTES);     // 2 MB
    unsigned short* VTw = (unsigned short*)((char*)d_ws + 2 * SB_BYTES); // 2 MB
    float* Ksum = (float*)((char*)d_ws + 3 * SB_BYTES);                  // 32 KB

    k1<<<dim3(NC, Bc, 4), 512, 0, stream>>>(K, V, SBw, Ksum, KBw, VTw);
    int totalThreads = Bc * D * D / 8 + Bc * D / 4;        // 4096 + 64
    k_scan<<<dim3((totalThreads + 255) / 256), 256, 0, stream>>>(SBw, Ksum);
    k_out<<<dim3(NC, Bc, 4), 512, 0, stream>>>(Q, KBw, VTw, SBw, Ksum, Out);
}